// Round 6
// baseline (53.823 us; speedup 1.0000x reference)
//
#include <hip/hip_runtime.h>

// out[i][j] = x[i][j] + sum_p ln(p) * x[(i - p) mod 8192][j]
// x: (8192, 4096) fp32. Rolling-retirement sliding window, f32x2 lanes:
// each thread owns one f32x2 column slot and R=32 consecutive output rows.
// acc[i] completes at t = i+19 (shift-0 is its last contribution) -> store
// immediately, so only ~20 accumulators are live regardless of R.
// R=32 cuts loads/output to (32+19)/32 = 1.59. launch_bounds(256,8) keeps
// VGPR <= 64 -> 8 waves/SIMD; grid 2048 x 4 waves = 8192 = 100% capacity.

#define ROWS 8192
#define COLS 4096
#define COLS2 (COLS / 2)   // 2048 f32x2 per row
#define LOG2_COLS2 11
#define R 32               // output rows per thread
#define MAXSHIFT 19
#define NXCD 8

typedef float f32x2 __attribute__((ext_vector_type(2)));

__constant__ constexpr int   SHIFT[9] = {0, 2, 3, 5, 7, 11, 13, 17, 19};
__constant__ constexpr float COEF[9]  = {
    1.0f,
    0.69314718055994530942f,  // ln 2
    1.09861228866810969140f,  // ln 3
    1.60943791243410037460f,  // ln 5
    1.94591014905531330511f,  // ln 7
    2.39789527279837054406f,  // ln 11
    2.56494935746153673605f,  // ln 13
    2.83321334405621608025f,  // ln 17
    2.94443897916644046001f   // ln 19
};

__global__ __launch_bounds__(256, 8) void spectral_kernel(
    const f32x2* __restrict__ x, f32x2* __restrict__ out) {
  // 2048 blocks; bijective XCD-contiguous swizzle (2048 % 8 == 0):
  // XCD k owns blocks k*256..k*256+255 -> contiguous rows, halo stays in L2.
  const int sblk = (blockIdx.x & (NXCD - 1)) * (2048 / NXCD) + (blockIdx.x >> 3);
  const int g = sblk * blockDim.x + threadIdx.x;
  const int j = g & (COLS2 - 1);            // f32x2 column slot
  const int b = (g >> LOG2_COLS2) * R;      // first output row of this thread

  f32x2 acc[R];
#pragma unroll
  for (int k = 0; k < R; ++k) acc[k] = (f32x2)(0.f);

#pragma unroll
  for (int t = 0; t < R + MAXSHIFT; ++t) {
    const int r = (b - MAXSHIFT + t) & (ROWS - 1);
    const f32x2 v = x[(r << LOG2_COLS2) + j];
#pragma unroll
    for (int s = 0; s < 9; ++s) {
      const int k = t - MAXSHIFT + SHIFT[s];   // output row (rel. to b) fed by v
      if (k >= 0 && k < R) {                   // folds at compile time
        acc[k] = v * COEF[s] + acc[k];
      }
    }
    // Rolling retirement: acc[t-MAXSHIFT] just received its final (shift-0)
    // contribution -> store now, freeing its registers.
    if (t >= MAXSHIFT) {
      const int k = t - MAXSHIFT;
      __builtin_nontemporal_store(acc[k], &out[((b + k) << LOG2_COLS2) + j]);
    }
  }
}

extern "C" void kernel_launch(void* const* d_in, const int* in_sizes, int n_in,
                              void* d_out, int out_size, void* d_ws, size_t ws_size,
                              hipStream_t stream) {
  const f32x2* x = (const f32x2*)d_in[0];
  f32x2* out = (f32x2*)d_out;
  const int total_threads = (ROWS / R) * COLS2;  // 256 * 2048 = 524288
  const int block = 256;
  const int grid = total_threads / block;        // 2048
  spectral_kernel<<<grid, block, 0, stream>>>(x, out);
}